// Round 1
// baseline (166.461 us; speedup 1.0000x reference)
//
#include <hip/hip_runtime.h>
#include <math.h>

#define N_OBJ 8192
#define N_SR  4096
#define N_V   4100
#define N_F   4096
#define EPSF  1e-8f

#define SR_CHUNK   256
#define N_SRCH     (N_SR / SR_CHUNK)     // 16
#define FACE_CHUNK 256
#define N_FCH      (N_F / FACE_CHUNK)    // 16

// ---------------- Kernel 1a: partial NN (obj-block x sr-chunk) ----------------
__global__ void __launch_bounds__(256) nn_partial(const float* __restrict__ obj,
                                                  const float* __restrict__ sr,
                                                  float* __restrict__ pd2,
                                                  int* __restrict__ pidx) {
    __shared__ float4 s_sr[SR_CHUNK];
    const int tid = threadIdx.x;
    const int ob = blockIdx.x * 256 + tid;
    const int chunk = blockIdx.y;
    const int sbase = chunk * SR_CHUNK;

    {
        int j = sbase + tid;
        float sx = sr[3 * j + 0], sy = sr[3 * j + 1], sz = sr[3 * j + 2];
        s_sr[tid] = make_float4(sx, sy, sz, sx * sx + sy * sy + sz * sz);
    }
    __syncthreads();

    const float ox = obj[3 * ob + 0], oy = obj[3 * ob + 1], oz = obj[3 * ob + 2];
    const float oo = ox * ox + oy * oy + oz * oz;

    float best = INFINITY;
    int bidx = 0;
#pragma unroll 8
    for (int j = 0; j < SR_CHUNK; ++j) {
        float4 s = s_sr[j];                       // wave-uniform -> LDS broadcast
        float d = ox * s.x + oy * s.y + oz * s.z;
        float d2 = (oo + s.w) - 2.0f * d;
        if (d2 < best) { best = d2; bidx = sbase + j; }   // strict < keeps first index
    }
    pd2[chunk * N_OBJ + ob] = best;
    pidx[chunk * N_OBJ + ob] = bidx;
}

// ---------------- Kernel 1b: merge partials, cmap, D-vector ----------------
__global__ void __launch_bounds__(256) nn_finish(const float* __restrict__ obj,
                                                 const float* __restrict__ sr,
                                                 const float* __restrict__ pd2,
                                                 const int* __restrict__ pidx,
                                                 float* __restrict__ out,
                                                 float4* __restrict__ Dws) {
    const int i = blockIdx.x * 256 + threadIdx.x;
    float best = INFINITY;
    int bidx = 0;
#pragma unroll
    for (int c = 0; c < N_SRCH; ++c) {            // ascending chunk: ties -> earliest
        float d = pd2[c * N_OBJ + i];
        if (d < best) { best = d; bidx = pidx[c * N_OBJ + i]; }
    }
    const float ox = obj[3 * i + 0], oy = obj[3 * i + 1], oz = obj[3 * i + 2];
    const float tx = sr[3 * bidx + 0], ty = sr[3 * bidx + 1], tz = sr[3 * bidx + 2];
    const float dx = tx - ox, dy = ty - oy, dz = tz - oz;
    Dws[i] = make_float4(dx, dy, dz, dx * dx + dy * dy + dz * dz);

    float nn = sqrtf(fmaxf(best, 0.0f));
    float sig = 1.0f / (1.0f + expf(-100.0f * nn));
    out[1 + i] = 1.0f - 2.0f * (sig - 0.5f);
}

// ---------------- Kernel 2a: per-face precompute (16 floats/face) ----------------
__global__ void __launch_bounds__(256) face_pre(const float* __restrict__ hv,
                                                const float* __restrict__ fn,
                                                const int* __restrict__ hf,
                                                float4* __restrict__ F) {
    const int f = blockIdx.x * 256 + threadIdx.x;
    const int i0 = hf[3 * f + 0], i1 = hf[3 * f + 1], i2 = hf[3 * f + 2];
    const float v0x = hv[3 * i0 + 0], v0y = hv[3 * i0 + 1], v0z = hv[3 * i0 + 2];
    const float v1x = hv[3 * i1 + 0], v1y = hv[3 * i1 + 1], v1z = hv[3 * i1 + 2];
    const float v2x = hv[3 * i2 + 0], v2y = hv[3 * i2 + 1], v2z = hv[3 * i2 + 2];
    const float nx = fn[3 * f + 0], ny = fn[3 * f + 1], nz = fn[3 * f + 2];

    float num0 = v0x * nx + v0y * ny + v0z * nz;
    F[4 * f + 0] = make_float4(nx, ny, nz, num0);

    // edge (v0 -> v1): c = cross(n, v1-v0), s = dot(v0, c)
    {
        float ex = v1x - v0x, ey = v1y - v0y, ez = v1z - v0z;
        float cx = ny * ez - nz * ey;
        float cy = nz * ex - nx * ez;
        float cz = nx * ey - ny * ex;
        float s = v0x * cx + v0y * cy + v0z * cz;
        F[4 * f + 1] = make_float4(cx, cy, cz, s);
    }
    // edge (v1 -> v2): c = cross(n, v2-v1), s = dot(v1, c)
    {
        float ex = v2x - v1x, ey = v2y - v1y, ez = v2z - v1z;
        float cx = ny * ez - nz * ey;
        float cy = nz * ex - nx * ez;
        float cz = nx * ey - ny * ex;
        float s = v1x * cx + v1y * cy + v1z * cz;
        F[4 * f + 2] = make_float4(cx, cy, cz, s);
    }
    // edge (v2 -> v0): c = cross(n, v0-v2), s = dot(v2, c)
    {
        float ex = v0x - v2x, ey = v0y - v2y, ez = v0z - v2z;
        float cx = ny * ez - nz * ey;
        float cy = nz * ex - nx * ez;
        float cz = nx * ey - ny * ex;
        float s = v2x * cx + v2y * cy + v2z * cz;
        F[4 * f + 3] = make_float4(cx, cy, cz, s);
    }
}

// ---------------- Kernel 2b: ray-triangle parity counts ----------------
__global__ void __launch_bounds__(256) ray_count(const float* __restrict__ obj,
                                                 const float4* __restrict__ Dws,
                                                 const float4* __restrict__ F,
                                                 int* __restrict__ hits) {
    __shared__ float4 sF4[FACE_CHUNK * 4];        // 16 KB
    const int tid = threadIdx.x;
    const int ob = blockIdx.x * 256 + tid;
    const int fbase = blockIdx.y * FACE_CHUNK;

    // stage face table: coalesced float loads, stride-1 LDS writes (conflict-free)
    {
        float* sf = (float*)sF4;
        const float* Ff = (const float*)F + fbase * 16;
#pragma unroll
        for (int i = 0; i < FACE_CHUNK * 16 / 256; ++i)
            sf[i * 256 + tid] = Ff[i * 256 + tid];
    }
    __syncthreads();

    const float ox = obj[3 * ob + 0], oy = obj[3 * ob + 1], oz = obj[3 * ob + 2];
    const float4 Dv = Dws[ob];
    const float dx = Dv.x, dy = Dv.y, dz = Dv.z;

    int count = 0;
#pragma unroll 4
    for (int f = 0; f < FACE_CHUNK; ++f) {
        float4 Fn = sF4[4 * f + 0];               // wave-uniform -> broadcast
        float4 C1 = sF4[4 * f + 1];
        float4 C2 = sF4[4 * f + 2];
        float4 C3 = sF4[4 * f + 3];

        float denom = Fn.x * dx + Fn.y * dy + Fn.z * dz;
        float num = Fn.w - (Fn.x * ox + Fn.y * oy + Fn.z * oz);
        float t = num * __builtin_amdgcn_rcpf(denom);
        bool ok = (fabsf(denom) > EPSF) && (t > EPSF);

        float e1 = fmaf(t, C1.x * dx + C1.y * dy + C1.z * dz,
                        (C1.x * ox + C1.y * oy + C1.z * oz) - C1.w);
        float e2 = fmaf(t, C2.x * dx + C2.y * dy + C2.z * dz,
                        (C2.x * ox + C2.y * oy + C2.z * oz) - C2.w);
        float e3 = fmaf(t, C3.x * dx + C3.y * dy + C3.z * dz,
                        (C3.x * ox + C3.y * oy + C3.z * oz) - C3.w);

        count += (ok && (e1 >= 0.0f) && (e2 >= 0.0f) && (e3 >= 0.0f)) ? 1 : 0;
    }
    atomicAdd(&hits[ob], count);
}

// ---------------- Kernel 3: pen_dist reduction (deterministic, 1 block) ----------------
__global__ void __launch_bounds__(256) finalize(const float4* __restrict__ Dws,
                                                const int* __restrict__ hits,
                                                float* __restrict__ out) {
    __shared__ float wsum[4];
    const int tid = threadIdx.x;
    float s = 0.0f;
    for (int k = tid; k < N_OBJ; k += 256) {
        if (hits[k] & 1) s += Dws[k].w;
    }
#pragma unroll
    for (int off = 32; off > 0; off >>= 1) s += __shfl_down(s, off);
    if ((tid & 63) == 0) wsum[tid >> 6] = s;
    __syncthreads();
    if (tid == 0) {
        float tot = wsum[0] + wsum[1] + wsum[2] + wsum[3];
        out[0] = sqrtf(tot + 1e-12f);
    }
}

extern "C" void kernel_launch(void* const* d_in, const int* in_sizes, int n_in,
                              void* d_out, int out_size, void* d_ws, size_t ws_size,
                              hipStream_t stream) {
    const float* obj = (const float*)d_in[0];
    const float* sr  = (const float*)d_in[1];
    const float* hv  = (const float*)d_in[2];
    const float* fn  = (const float*)d_in[3];
    const int*   hf  = (const int*)d_in[4];
    float* out = (float*)d_out;

    char* ws = (char*)d_ws;
    float4* Dws = (float4*)(ws + 0);                        // 8192*16  = 128 KB
    int*    hits = (int*)(ws + 131072);                     // 8192*4   = 32 KB
    float*  pd2 = (float*)(ws + 163840);                    // 16*8192*4 = 512 KB
    int*    pidx = (int*)(ws + 163840 + 524288);            // 512 KB
    float4* F   = (float4*)(ws + 163840);                   // aliases pd2 (used after)

    nn_partial<<<dim3(N_OBJ / 256, N_SRCH), 256, 0, stream>>>(obj, sr, pd2, pidx);
    nn_finish<<<N_OBJ / 256, 256, 0, stream>>>(obj, sr, pd2, pidx, out, Dws);
    face_pre<<<N_F / 256, 256, 0, stream>>>(hv, fn, hf, F);
    hipMemsetAsync(hits, 0, N_OBJ * sizeof(int), stream);
    ray_count<<<dim3(N_OBJ / 256, N_FCH), 256, 0, stream>>>(obj, Dws, F, hits);
    finalize<<<1, 256, 0, stream>>>(Dws, hits, out);
}